// Round 1
// baseline (213.156 us; speedup 1.0000x reference)
//
#include <hip/hip_runtime.h>

#define NB   256     // bins per batch
#define BPB  128     // blocks per batch
#define TPB  256     // threads per block
#define BIGF 1e30f   // matches reference BIG
#define SENT 1e19f   // sentinel for invalid points: (c-SENT)^2 ~ 1e38, finite, loses every min

__global__ void init_binmin(unsigned int* __restrict__ binmin, int n) {
    int i = blockIdx.x * blockDim.x + threadIdx.x;
    if (i < n) binmin[i] = __float_as_uint(BIGF);
}

__global__ __launch_bounds__(TPB) void chamfer_main(
    const float* __restrict__ bc, const float* __restrict__ gt,
    int V, int chunk,
    float* __restrict__ sumA_part, int* __restrict__ cnt_part,
    unsigned int* __restrict__ binmin)
{
    const int b   = blockIdx.x / BPB;
    const int blk = blockIdx.x % BPB;
    const int tid = threadIdx.x;

    __shared__ float s_c[NB];    // bin centers for this batch
    __shared__ float rs[TPB];    // reduction scratch (float)
    __shared__ int   ri[TPB];    // reduction scratch (int)
    extern __shared__ float s_p[];  // staged points (chunk floats)

    if (tid < NB) s_c[tid] = bc[b * NB + tid];

    const int start = blk * chunk;
    const int cn = min(chunk, V - start);   // points in this block's chunk

    // stage points into LDS, sanitize invalid ones, count valid
    int cnt = 0;
    const float* gp = gt + (size_t)b * V + start;
    for (int i = tid; i < cn; i += TPB) {
        float p = gp[i];
        bool valid = (p >= 0.001f);
        cnt += valid ? 1 : 0;
        s_p[i] = valid ? p : SENT;
    }
    __syncthreads();

    // direction 1: each valid point -> nearest bin center (sum of min dists)
    float sum = 0.f;
    for (int i = tid; i < cn; i += TPB) {
        float p = s_p[i];
        if (p < 1e18f) {   // valid
            float dmin = BIGF;
            #pragma unroll 8
            for (int j = 0; j < NB; ++j) {
                float d = s_c[j] - p;   // LDS broadcast: all lanes read same j
                dmin = fminf(dmin, d * d);
            }
            sum += dmin;
        }
    }

    // direction 2: bin `tid` -> nearest valid point in this chunk
    // sentinel points give d^2 ~ 1e38 and never win the min
    float m = BIGF;
    float c = s_c[tid];
    for (int i = 0; i < cn; ++i) {
        float d = c - s_p[i];   // LDS broadcast: all lanes read same i
        m = fminf(m, d * d);
    }
    // nonnegative floats order identically as unsigned ints -> uint atomicMin == float min
    atomicMin(&binmin[b * NB + tid], __float_as_uint(m));

    // deterministic block reduction of direction-1 sum and valid count
    rs[tid] = sum; ri[tid] = cnt;
    __syncthreads();
    for (int s = TPB / 2; s > 0; s >>= 1) {
        if (tid < s) { rs[tid] += rs[tid + s]; ri[tid] += ri[tid + s]; }
        __syncthreads();
    }
    if (tid == 0) {
        sumA_part[b * BPB + blk] = rs[0];
        cnt_part [b * BPB + blk] = ri[0];
    }
}

__global__ __launch_bounds__(256) void chamfer_finalize(
    const float* __restrict__ bc,
    const float* __restrict__ sumA_part, const int* __restrict__ cnt_part,
    const unsigned int* __restrict__ binmin,
    int B, float* __restrict__ out)
{
    __shared__ float rs[256];
    __shared__ float rm[256];
    __shared__ int   ri[256];
    __shared__ int   n[8];
    __shared__ float sA[8];
    const int tid = threadIdx.x;

    // per-batch valid count n[b] and direction-1 partial sum
    for (int b = 0; b < B; ++b) {
        ri[tid] = (tid < BPB) ? cnt_part [b * BPB + tid] : 0;
        rs[tid] = (tid < BPB) ? sumA_part[b * BPB + tid] : 0.f;
        __syncthreads();
        for (int s = 128; s > 0; s >>= 1) {
            if (tid < s) { ri[tid] += ri[tid + s]; rs[tid] += rs[tid + s]; }
            __syncthreads();
        }
        if (tid == 0) { n[b] = ri[0]; sA[b] = rs[0]; }
        __syncthreads();
    }

    int Lmax = 0;
    for (int b = 0; b < B; ++b) Lmax = max(Lmax, n[b]);

    float total = 0.f;
    for (int b = 0; b < B; ++b) {
        const int npad = Lmax - n[b];
        const float c  = bc[b * NB + tid];   // NB == blockDim.x
        const float c2 = c * c;
        float bm = __uint_as_float(binmin[b * NB + tid]);
        if (npad > 0) bm = fminf(bm, c2);    // pad points sit at 0 -> dist c^2
        rs[tid] = bm;   // sumB terms
        rm[tid] = c2;   // for min_j c_j^2 (pad-point contribution to sumA)
        __syncthreads();
        for (int s = 128; s > 0; s >>= 1) {
            if (tid < s) { rs[tid] += rs[tid + s]; rm[tid] = fminf(rm[tid], rm[tid + s]); }
            __syncthreads();
        }
        if (tid == 0) total += sA[b] + (float)npad * rm[0] + rs[0];
        __syncthreads();
    }
    if (tid == 0) out[0] = total / (float)B;   // batch_reduction = mean
}

extern "C" void kernel_launch(void* const* d_in, const int* in_sizes, int n_in,
                              void* d_out, int out_size, void* d_ws, size_t ws_size,
                              hipStream_t stream) {
    const float* bc = (const float*)d_in[0];   // [B, 256, 1]
    const float* gt = (const float*)d_in[1];   // [B, 1, H, W]
    const int B = in_sizes[0] / NB;            // 4
    const int V = in_sizes[1] / B;             // 157696
    const int chunk = (V + BPB - 1) / BPB;     // 1232

    float*        sumA_part = (float*)d_ws;
    int*          cnt_part  = (int*)(sumA_part + B * BPB);
    unsigned int* binmin    = (unsigned int*)(cnt_part + B * BPB);

    init_binmin<<<(B * NB + 255) / 256, 256, 0, stream>>>(binmin, B * NB);
    chamfer_main<<<B * BPB, TPB, chunk * (int)sizeof(float), stream>>>(
        bc, gt, V, chunk, sumA_part, cnt_part, binmin);
    chamfer_finalize<<<1, 256, 0, stream>>>(bc, sumA_part, cnt_part, binmin, B, (float*)d_out);
}

// Round 2
// 146.506 us; speedup vs baseline: 1.4549x; 1.4549x over previous
//
#include <hip/hip_runtime.h>

#define NB   256     // bins per batch
#define BPB  128     // blocks per batch (157696 = 128 * 1232 exactly)
#define TPB  256     // threads per block
#define PP   5       // max points per thread (1232 = 4*256 + 208)

__global__ __launch_bounds__(TPB) void chamfer_fused(
    const float* __restrict__ bc, const float* __restrict__ gt,
    int B, int V, int CH,
    float* __restrict__ sumA_part, int* __restrict__ cnt_part,
    unsigned int* __restrict__ binmin, unsigned int* __restrict__ counter,
    float* __restrict__ out)
{
    const int b   = blockIdx.x >> 7;       // BPB == 128
    const int blk = blockIdx.x & (BPB - 1);
    const int tid = threadIdx.x;
    const int start = blk * CH;
    const int cn = min(CH, V - start);

    const float* __restrict__ cb = bc + b * NB;
    const float* __restrict__ gp = gt + (size_t)b * V + start;

    __shared__ float rs[TPB];
    __shared__ float rm[TPB];
    __shared__ int   ri[TPB];
    __shared__ int   sn[8];
    __shared__ float ssa[8];

    const unsigned PB = __float_as_uint(0.001f);
    const unsigned SB = __float_as_uint(1e18f);   // sentinel: d^2 ~ 1e36, finite, loses every min

    // ---- per-thread points (strided by TPB), sanitized, in registers ----
    float p[PP];
    bool  va[PP];
    int cnt = 0;
    #pragma unroll
    for (int k = 0; k < PP; ++k) {
        int idx = tid + k * TPB;
        bool in = idx < cn;
        float v = in ? gp[idx] : 0.f;
        bool ok = in && (v >= 0.001f);
        va[k] = ok;
        cnt += ok ? 1 : 0;
        p[k] = ok ? v : 1e18f;
    }

    // ---- direction 1: each point -> nearest bin center ----
    // bin stream is wave-uniform -> scalar loads; 5 independent min chains
    float dm[PP];
    #pragma unroll
    for (int k = 0; k < PP; ++k) dm[k] = 1e30f;
    #pragma unroll 4
    for (int j = 0; j < NB; ++j) {
        float cj = cb[j];                  // uniform -> s_load
        #pragma unroll
        for (int k = 0; k < PP; ++k) {
            float d = cj - p[k];
            dm[k] = fminf(dm[k], d * d);
        }
    }
    float sum = 0.f;
    #pragma unroll
    for (int k = 0; k < PP; ++k) sum += va[k] ? dm[k] : 0.f;

    // ---- direction 2: bin `tid` -> nearest point in this chunk ----
    // point stream is wave-uniform -> scalar loads; validity via uint-bits compare
    const unsigned* __restrict__ gbits = (const unsigned*)gp;
    const float c = cb[tid];
    float m0 = 1e30f, m1 = 1e30f, m2 = 1e30f, m3 = 1e30f;
    int i = 0;
    for (; i + 4 <= cn; i += 4) {
        unsigned b0 = gbits[i], b1 = gbits[i+1], b2 = gbits[i+2], b3 = gbits[i+3];
        float p0 = __uint_as_float(b0 >= PB ? b0 : SB);
        float p1 = __uint_as_float(b1 >= PB ? b1 : SB);
        float p2 = __uint_as_float(b2 >= PB ? b2 : SB);
        float p3 = __uint_as_float(b3 >= PB ? b3 : SB);
        float d0 = c - p0; m0 = fminf(m0, d0 * d0);
        float d1 = c - p1; m1 = fminf(m1, d1 * d1);
        float d2 = c - p2; m2 = fminf(m2, d2 * d2);
        float d3 = c - p3; m3 = fminf(m3, d3 * d3);
    }
    for (; i < cn; ++i) {
        unsigned b0 = gbits[i];
        float p0 = __uint_as_float(b0 >= PB ? b0 : SB);
        float d0 = c - p0; m0 = fminf(m0, d0 * d0);
    }
    float m = fminf(fminf(m0, m1), fminf(m2, m3));
    // nonneg float ordering == uint ordering; min is exact -> deterministic
    atomicMin(&binmin[b * NB + tid], __float_as_uint(m));

    // ---- deterministic block reduction of dir-1 sum + valid count ----
    rs[tid] = sum; ri[tid] = cnt;
    __syncthreads();
    for (int s = TPB / 2; s > 0; s >>= 1) {
        if (tid < s) { rs[tid] += rs[tid + s]; ri[tid] += ri[tid + s]; }
        __syncthreads();
    }
    if (tid == 0) {
        sumA_part[b * BPB + blk] = rs[0];
        cnt_part [b * BPB + blk] = ri[0];
    }

    // ---- last-block-done finalize ----
    __threadfence();                       // release: partials + atomics visible device-wide
    __shared__ unsigned s_last;
    if (tid == 0) s_last = atomicAdd(counter, 1u);
    __syncthreads();
    if (s_last != gridDim.x - 1) return;
    __threadfence();                       // acquire: see all other blocks' writes

    // per-batch valid count n[b] and dir-1 sum
    for (int bb = 0; bb < B; ++bb) {
        ri[tid] = (tid < BPB) ? cnt_part [bb * BPB + tid] : 0;
        rs[tid] = (tid < BPB) ? sumA_part[bb * BPB + tid] : 0.f;
        __syncthreads();
        for (int s = TPB / 2; s > 0; s >>= 1) {
            if (tid < s) { ri[tid] += ri[tid + s]; rs[tid] += rs[tid + s]; }
            __syncthreads();
        }
        if (tid == 0) { sn[bb] = ri[0]; ssa[bb] = rs[0]; }
        __syncthreads();
    }

    int Lmax = 0;
    for (int bb = 0; bb < B; ++bb) Lmax = max(Lmax, sn[bb]);

    float total = 0.f;
    for (int bb = 0; bb < B; ++bb) {
        const int   npad = Lmax - sn[bb];
        const float cc   = bc[bb * NB + tid];
        const float c2   = cc * cc;
        float bm = __uint_as_float(binmin[bb * NB + tid]);
        if (npad > 0) bm = fminf(bm, c2);  // pad points sit at 0 -> dist c^2
        rs[tid] = bm;                      // sumB terms
        rm[tid] = c2;                      // min_j c_j^2 for pad contribution to sumA
        __syncthreads();
        for (int s = TPB / 2; s > 0; s >>= 1) {
            if (tid < s) { rs[tid] += rs[tid + s]; rm[tid] = fminf(rm[tid], rm[tid + s]); }
            __syncthreads();
        }
        if (tid == 0) total += ssa[bb] + (float)npad * rm[0] + rs[0];
        __syncthreads();
    }
    if (tid == 0) out[0] = total / (float)B;   // batch_reduction = mean
}

extern "C" void kernel_launch(void* const* d_in, const int* in_sizes, int n_in,
                              void* d_out, int out_size, void* d_ws, size_t ws_size,
                              hipStream_t stream) {
    const float* bc = (const float*)d_in[0];   // [B, 256, 1]
    const float* gt = (const float*)d_in[1];   // [B, 1, H, W]
    const int B  = in_sizes[0] / NB;           // 4
    const int V  = in_sizes[1] / B;            // 157696 = 128 * 1232
    const int CH = (V + BPB - 1) / BPB;        // 1232  (PP*TPB=1280 covers it)

    float*        sumA_part = (float*)d_ws;
    int*          cnt_part  = (int*)(sumA_part + B * BPB);
    unsigned int* binmin    = (unsigned int*)(cnt_part + B * BPB);
    unsigned int* counter   = binmin + B * NB;

    // 0xFFFFFFFF == uint max -> identity for uint atomicMin on nonneg float bits
    hipMemsetAsync(binmin, 0xFF, (size_t)B * NB * sizeof(unsigned int), stream);
    hipMemsetAsync(counter, 0, sizeof(unsigned int), stream);

    chamfer_fused<<<B * BPB, TPB, 0, stream>>>(
        bc, gt, B, V, CH, sumA_part, cnt_part, binmin, counter, (float*)d_out);
}